// Round 5
// baseline (188.933 us; speedup 1.0000x reference)
//
#include <hip/hip_runtime.h>
#include <stdint.h>

typedef __attribute__((ext_vector_type(8))) short short8;
typedef __attribute__((ext_vector_type(8))) unsigned short ushort8;
typedef __attribute__((ext_vector_type(4))) float floatx4;

#define W_DIM 900
#define NPAD  450
#define TM    256
#define TN    128
// Tiled bf16 layout per input: [b][slab 0..31][row 0..1023][32 elems];
// within a row the four 8-elem chunks sit at position chunk^(row&3)
// (XOR swizzle -> conflict-free LDS frag reads after a linear DMA copy).
#define SLAB_E   32768              // 1024*32 elems per slab
#define BATCH_E  1048576            // 32 slabs per batch

__device__ __forceinline__ unsigned short f2bf(float f) {
  unsigned int u = __builtin_bit_cast(unsigned int, f);
  return (unsigned short)((u + 0x8000u) >> 16);   // round-half-up
}

__device__ __forceinline__ void async16(const void* g, void* l) {
  __builtin_amdgcn_global_load_lds(
      (const __attribute__((address_space(1))) void*)g,
      (__attribute__((address_space(3))) void*)l, 16, 0, 0);
}

// ---------------------------------------------------------------------------
// Convert fp32 [b,h,w,c] -> tiled bf16, w padded 900->1024 with zeros.
// grid (16 wtiles, 4 h, 32 b|input), 256 threads.
// Phase 1: ALL 16 float4 loads hoisted into live regs (16 outstanding/thread
// -> latency hidden; r4's version had VGPR=12 and ~2 outstanding = 53 us).
// Phase 2: LDS transpose -> 4 KB contiguous global stores.
// ---------------------------------------------------------------------------
__global__ void convert_kernel(const float* __restrict__ X1,
                               const float* __restrict__ X2,
                               unsigned short* __restrict__ dA,
                               unsigned short* __restrict__ dB) {
  const int wt = blockIdx.x;           // 64-row w tile
  const int h  = blockIdx.y;
  const int bz = blockIdx.z;
  const int b  = bz & 15;
  const float* __restrict__ src = (bz >> 4) ? X2 : X1;
  unsigned short* __restrict__ dst = (bz >> 4) ? dB : dA;

  __shared__ __align__(16) unsigned short T[64 * 264];  // 33792 B

  const int t   = threadIdx.x;
  const int c8  = (t & 31) << 3;       // 0..248 step 8
  const int wl0 = t >> 5;              // 0..7

  const float4 fz = make_float4(0.f, 0.f, 0.f, 0.f);
  float4 v[16];
#pragma unroll
  for (int i = 0; i < 8; ++i) {
    const int wg = wt * 64 + i * 8 + wl0;
    v[2 * i] = fz; v[2 * i + 1] = fz;
    if (wg < W_DIM) {
      const float* p = src + (((size_t)(b * 4 + h) * W_DIM + wg) << 8) + c8;
      v[2 * i]     = *(const float4*)p;
      v[2 * i + 1] = *(const float4*)(p + 4);
    }
  }
#pragma unroll
  for (int i = 0; i < 8; ++i) {
    ushort8 o;
    o[0] = f2bf(v[2*i].x);   o[1] = f2bf(v[2*i].y);
    o[2] = f2bf(v[2*i].z);   o[3] = f2bf(v[2*i].w);
    o[4] = f2bf(v[2*i+1].x); o[5] = f2bf(v[2*i+1].y);
    o[6] = f2bf(v[2*i+1].z); o[7] = f2bf(v[2*i+1].w);
    *(ushort8*)&T[(i * 8 + wl0) * 264 + c8] = o;
  }
  __syncthreads();

  const int wl = t >> 2;               // 0..63
  const int wg = wt * 64 + wl;
  const int ch = t & 3;                // stored chunk position
  const int c0 = ch ^ (wl & 3);        // original chunk ((wg&3)==(wl&3))
#pragma unroll
  for (int s = 0; s < 8; ++s) {
    ushort8 vv = *(const ushort8*)&T[wl * 264 + s * 32 + c0 * 8];
    const size_t off =
        ((size_t)b * BATCH_E) + (size_t)(h * 8 + s) * SLAB_E + (size_t)wg * 32 + ch * 8;
    *(ushort8*)&dst[off] = vv;         // contiguous 4 KB per iteration
  }
}

// ---------------------------------------------------------------------------
// Batched gram GEMM + fused circular-band reduce, reading tiled bf16.
// Tile 256x128, BK=32, TRUE double-buffered LDS (2 x 24 KB), ONE barrier per
// kt: prefetch slab kt+1 issued before the MFMA phase, so the vmcnt drain at
// the barrier is covered by compute. grid 512, x = (it*8+jt)*16 + b so
// x%8 = b%8 -> all blocks of a batch share an XCD (tile re-reads = L2 hits).
// 4 waves; wave (wm,wn) = 128x64 quadrant, 8x4 frags mfma 16x16x32_bf16.
// ---------------------------------------------------------------------------
__global__ __launch_bounds__(256, 2)
void gemm_band_kernel(const unsigned short* __restrict__ A,
                      const unsigned short* __restrict__ B,
                      float* __restrict__ out) {
  const int x    = blockIdx.x;
  const int b    = x & 15;
  const int pair = x >> 4;
  const int it   = pair >> 3;          // 0..3
  const int jt   = pair & 7;           // 0..7

  __shared__ __align__(16) unsigned char smem[49152];
  unsigned short* SB = (unsigned short*)smem;
  // buffer sel*12288 elems: A region [0,8192), B region [8192,12288)

  const int tid  = threadIdx.x;
  const int lane = tid & 63;
  const int warp = tid >> 6;
  const int wm   = warp >> 1;
  const int wn   = warp & 1;

  const unsigned short* gA =
      A + (size_t)b * BATCH_E + (size_t)(it * TM + warp * 64) * 32 + lane * 8;
  const unsigned short* gB =
      B + (size_t)b * BATCH_E + (size_t)(jt * TN + warp * 32) * 32 + lane * 8;
  const int lAoff = warp * 2048 + lane * 8;          // in A region
  const int lBoff = 8192 + warp * 1024 + lane * 8;   // in B region

  floatx4 acc[8][4];
#pragma unroll
  for (int i = 0; i < 8; ++i)
#pragma unroll
    for (int j = 0; j < 4; ++j) acc[i][j] = (floatx4)0.0f;

  const int quad = lane >> 4;
  const int r16  = lane & 15;
  const int csw  = (quad ^ (r16 & 3)) * 8;           // XOR-swizzled chunk
  const int aBase = (wm * 128 + r16) * 32 + csw;
  const int bBase = 8192 + (wn * 64 + r16) * 32 + csw;

  // Prologue: stage slab 0 into buffer 0.
#pragma unroll
  for (int g = 0; g < 4; ++g) async16(gA + g * 512, SB + lAoff + g * 512);
#pragma unroll
  for (int g = 0; g < 2; ++g) async16(gB + g * 512, SB + lBoff + g * 512);
  __syncthreads();

  for (int kt = 0; kt < 32; ++kt) {
    const int cur = (kt & 1) * 12288;
    const int nxt = 12288 - cur;
    if (kt < 31) {
      // Prefetch slab kt+1 into the other buffer (its previous contents were
      // fully read before the barrier ending iteration kt-1).
      const size_t ko = (size_t)(kt + 1) * SLAB_E;
#pragma unroll
      for (int g = 0; g < 4; ++g)
        async16(gA + ko + g * 512, SB + nxt + lAoff + g * 512);
#pragma unroll
      for (int g = 0; g < 2; ++g)
        async16(gB + ko + g * 512, SB + nxt + lBoff + g * 512);
    }

    short8 af[8], bf[4];
#pragma unroll
    for (int mi = 0; mi < 8; ++mi)
      af[mi] = *(const short8*)(SB + cur + aBase + mi * 512);
#pragma unroll
    for (int ni = 0; ni < 4; ++ni)
      bf[ni] = *(const short8*)(SB + cur + bBase + ni * 512);
#pragma unroll
    for (int mi = 0; mi < 8; ++mi)
#pragma unroll
      for (int ni = 0; ni < 4; ++ni)
        acc[mi][ni] = __builtin_amdgcn_mfma_f32_16x16x32_bf16(
            af[mi], bf[ni], acc[mi][ni], 0, 0, 0);

    __syncthreads();   // frag reads done + prefetch drained (covered by MFMA)
  }

  // ---- Epilogue: gram[i,j] -> out[b, (i-j-450) mod 900]; 4 passes of 64 rows.
  float* Ep = (float*)smem;            // [64][132] aliases staging (dead now)
  const int dbase = it * TM - jt * TN - NPAD;

  for (int p = 0; p < 4; ++p) {
    if (wm == (p >> 1)) {
      const int mib = (p & 1) * 4;
#pragma unroll
      for (int mo = 0; mo < 4; ++mo)
#pragma unroll
        for (int ni = 0; ni < 4; ++ni)
#pragma unroll
          for (int rr = 0; rr < 4; ++rr) {
            const int lr = mo * 16 + quad * 4 + rr;
            const int c  = wn * 64 + ni * 16 + r16;
            Ep[lr * 132 + c] = acc[mib + mo][ni][rr];
          }
    }
    __syncthreads();
    if (tid < 191) {
      const int d = tid - 127;
      int k0 = d > 0 ? d : 0;
      int k1 = 128 + d; if (k1 > 64) k1 = 64;
      float s = 0.0f;
      for (int k = k0; k < k1; ++k) s += Ep[k * 132 + (k - d)];
      int dg = dbase + p * 64 + d;
      int sidx = dg % W_DIM;
      if (sidx < 0) sidx += W_DIM;
      atomicAdd(&out[b * W_DIM + sidx], s);
    }
    __syncthreads();
  }
}

// ---------------------------------------------------------------------------
// Fallback (workspace too small): direct fp32.
// ---------------------------------------------------------------------------
__global__ void naive_kernel(const float* __restrict__ x1,
                             const float* __restrict__ x2,
                             float* __restrict__ out) {
  const int s = blockIdx.x;
  const int b = blockIdx.y;
  const int c = threadIdx.x;
  float acc = 0.0f;
  for (int h = 0; h < 4; ++h) {
    const float* p1 = x1 + (size_t)(b * 4 + h) * W_DIM * 256;
    const float* p2 = x2 + (size_t)(b * 4 + h) * W_DIM * 256;
    for (int w = 0; w < W_DIM; ++w) {
      int w1 = s + w + NPAD;
      if (w1 >= W_DIM) w1 -= W_DIM;
      if (w1 >= W_DIM) w1 -= W_DIM;
      acc += p1[(size_t)w1 * 256 + c] * p2[(size_t)w * 256 + c];
    }
  }
  for (int off = 32; off > 0; off >>= 1) acc += __shfl_down(acc, off, 64);
  __shared__ float red[4];
  if ((threadIdx.x & 63) == 0) red[threadIdx.x >> 6] = acc;
  __syncthreads();
  if (threadIdx.x == 0)
    out[b * W_DIM + s] = red[0] + red[1] + red[2] + red[3];
}

extern "C" void kernel_launch(void* const* d_in, const int* in_sizes, int n_in,
                              void* d_out, int out_size, void* d_ws, size_t ws_size,
                              hipStream_t stream) {
  const float* x1 = (const float*)d_in[0];
  const float* x2 = (const float*)d_in[1];
  float* out = (float*)d_out;

  hipMemsetAsync(d_out, 0, (size_t)out_size * sizeof(float), stream);

  const size_t need = (size_t)2 * 16 * BATCH_E * sizeof(unsigned short); // 64 MiB
  if (ws_size >= need) {
    unsigned short* dA = (unsigned short*)d_ws;
    unsigned short* dB = dA + (size_t)16 * BATCH_E;
    convert_kernel<<<dim3(16, 4, 32), 256, 0, stream>>>(x1, x2, dA, dB);
    gemm_band_kernel<<<dim3(512), 256, 0, stream>>>(dA, dB, out);
  } else {
    naive_kernel<<<dim3(W_DIM, 16), 256, 0, stream>>>(x1, x2, out);
  }
}

// Round 6
// 182.206 us; speedup vs baseline: 1.0369x; 1.0369x over previous
//
#include <hip/hip_runtime.h>
#include <stdint.h>

typedef __attribute__((ext_vector_type(8))) short short8;
typedef __attribute__((ext_vector_type(8))) unsigned short ushort8;
typedef __attribute__((ext_vector_type(4))) float floatx4;

#define W_DIM 900
#define NPAD  450
#define TM    256
#define TN    128
// Tiled bf16 layout per input: [b][slab 0..31][row 0..1023][32 elems];
// slab = h*8 + c32chunk; within a row the four 8-elem chunks sit at position
// chunk^(row&3) (XOR swizzle -> conflict-free LDS frag reads after linear DMA).
#define SLAB_E   32768              // 1024*32 elems per slab
#define BATCH_E  1048576            // 32 slabs per batch

__device__ __forceinline__ unsigned short f2bf(float f) {
  unsigned int u = __builtin_bit_cast(unsigned int, f);
  return (unsigned short)((u + 0x8000u) >> 16);   // round-half-up
}

__device__ __forceinline__ void async16(const void* g, void* l) {
  __builtin_amdgcn_global_load_lds(
      (const __attribute__((address_space(1))) void*)g,
      (__attribute__((address_space(3))) void*)l, 16, 0, 0);
}

// ---------------------------------------------------------------------------
// Convert fp32 [b,h,w,c] -> tiled bf16 (layout above), w padded 900->1024.
// v3: NO LDS, NO barrier (r4/r5 were occupancy-capped at 2.4 blocks/CU by the
// 33 KB transpose buffer -> latency-bound at 2.37 TB/s). Reads stay 2 KB
// contiguous per wave-iter; each thread stores its 16 B chunk directly to the
// tiled destination (64-B segments, full write-granule utilization).
// grid (16 wtiles, 4 h, 32 b|input), 256 threads, 8 independent iters.
// ---------------------------------------------------------------------------
__global__ void convert_kernel(const float* __restrict__ X1,
                               const float* __restrict__ X2,
                               unsigned short* __restrict__ dA,
                               unsigned short* __restrict__ dB) {
  const int wt = blockIdx.x;           // 64-row w tile
  const int h  = blockIdx.y;
  const int bz = blockIdx.z;
  const int b  = bz & 15;
  const float* __restrict__ src = (bz >> 4) ? X2 : X1;
  unsigned short* __restrict__ dst = (bz >> 4) ? dB : dA;

  const int t   = threadIdx.x;
  const int q   = t & 31;              // c-chunk-of-8 index (c = q*8)
  const int wl0 = t >> 5;              // 0..7
  const int Q   = q >> 2;              // c32 chunk -> slab component
  const int p0  = q & 3;               // chunk position within 32-elem group

  const size_t srow = (size_t)(b * 4 + h) * W_DIM;
  const size_t dbas = (size_t)b * BATCH_E + (size_t)(h * 8 + Q) * SLAB_E;

  const float4 fz = make_float4(0.f, 0.f, 0.f, 0.f);
  float4 v[16];
  int wg[8];
#pragma unroll
  for (int i = 0; i < 8; ++i) {
    wg[i] = wt * 64 + i * 8 + wl0;
    v[2 * i] = fz; v[2 * i + 1] = fz;
    if (wg[i] < W_DIM) {
      const float* p = src + ((srow + wg[i]) << 8) + q * 8;
      v[2 * i]     = *(const float4*)p;
      v[2 * i + 1] = *(const float4*)(p + 4);
    }
  }
#pragma unroll
  for (int i = 0; i < 8; ++i) {
    ushort8 o;
    o[0] = f2bf(v[2*i].x);   o[1] = f2bf(v[2*i].y);
    o[2] = f2bf(v[2*i].z);   o[3] = f2bf(v[2*i].w);
    o[4] = f2bf(v[2*i+1].x); o[5] = f2bf(v[2*i+1].y);
    o[6] = f2bf(v[2*i+1].z); o[7] = f2bf(v[2*i+1].w);
    const size_t off = dbas + (size_t)wg[i] * 32 + (p0 ^ (wg[i] & 3)) * 8;
    *(ushort8*)&dst[off] = o;
  }
}

// ---------------------------------------------------------------------------
// Batched gram GEMM + fused circular-band reduce, reading tiled bf16.
// Tile 256x128, BK=32, double-buffered LDS (2 x 24 KB), one barrier per kt;
// prefetch kt+1 issued before the MFMA phase. grid 512, x = (it*8+jt)*16 + b
// so x%8 = b%8 -> all blocks of a batch share an XCD (tile re-reads = L2 hits).
// 4 waves; wave (wm,wn) = 128x64 quadrant, 8x4 frags mfma 16x16x32_bf16.
// ---------------------------------------------------------------------------
__global__ __launch_bounds__(256, 2)
void gemm_band_kernel(const unsigned short* __restrict__ A,
                      const unsigned short* __restrict__ B,
                      float* __restrict__ out) {
  const int x    = blockIdx.x;
  const int b    = x & 15;
  const int pair = x >> 4;
  const int it   = pair >> 3;          // 0..3
  const int jt   = pair & 7;           // 0..7

  __shared__ __align__(16) unsigned char smem[49152];
  unsigned short* SB = (unsigned short*)smem;
  // buffer sel*12288 elems: A region [0,8192), B region [8192,12288)

  const int tid  = threadIdx.x;
  const int lane = tid & 63;
  const int warp = tid >> 6;
  const int wm   = warp >> 1;
  const int wn   = warp & 1;

  const unsigned short* gA =
      A + (size_t)b * BATCH_E + (size_t)(it * TM + warp * 64) * 32 + lane * 8;
  const unsigned short* gB =
      B + (size_t)b * BATCH_E + (size_t)(jt * TN + warp * 32) * 32 + lane * 8;
  const int lAoff = warp * 2048 + lane * 8;          // in A region
  const int lBoff = 8192 + warp * 1024 + lane * 8;   // in B region

  floatx4 acc[8][4];
#pragma unroll
  for (int i = 0; i < 8; ++i)
#pragma unroll
    for (int j = 0; j < 4; ++j) acc[i][j] = (floatx4)0.0f;

  const int quad = lane >> 4;
  const int r16  = lane & 15;
  const int csw  = (quad ^ (r16 & 3)) * 8;           // XOR-swizzled chunk
  const int aBase = (wm * 128 + r16) * 32 + csw;
  const int bBase = 8192 + (wn * 64 + r16) * 32 + csw;

  // Prologue: stage slab 0 into buffer 0.
#pragma unroll
  for (int g = 0; g < 4; ++g) async16(gA + g * 512, SB + lAoff + g * 512);
#pragma unroll
  for (int g = 0; g < 2; ++g) async16(gB + g * 512, SB + lBoff + g * 512);
  __syncthreads();

  for (int kt = 0; kt < 32; ++kt) {
    const int cur = (kt & 1) * 12288;
    const int nxt = 12288 - cur;
    if (kt < 31) {
      const size_t ko = (size_t)(kt + 1) * SLAB_E;
#pragma unroll
      for (int g = 0; g < 4; ++g)
        async16(gA + ko + g * 512, SB + nxt + lAoff + g * 512);
#pragma unroll
      for (int g = 0; g < 2; ++g)
        async16(gB + ko + g * 512, SB + nxt + lBoff + g * 512);
    }

    short8 af[8], bf[4];
#pragma unroll
    for (int mi = 0; mi < 8; ++mi)
      af[mi] = *(const short8*)(SB + cur + aBase + mi * 512);
#pragma unroll
    for (int ni = 0; ni < 4; ++ni)
      bf[ni] = *(const short8*)(SB + cur + bBase + ni * 512);
#pragma unroll
    for (int mi = 0; mi < 8; ++mi)
#pragma unroll
      for (int ni = 0; ni < 4; ++ni)
        acc[mi][ni] = __builtin_amdgcn_mfma_f32_16x16x32_bf16(
            af[mi], bf[ni], acc[mi][ni], 0, 0, 0);

    __syncthreads();   // frag reads done + prefetch drained (covered by MFMA)
  }

  // ---- Epilogue: gram[i,j] -> out[b, (i-j-450) mod 900]; 4 passes of 64 rows.
  float* Ep = (float*)smem;            // [64][132] aliases staging (dead now)
  const int dbase = it * TM - jt * TN - NPAD;

  for (int p = 0; p < 4; ++p) {
    if (wm == (p >> 1)) {
      const int mib = (p & 1) * 4;
#pragma unroll
      for (int mo = 0; mo < 4; ++mo)
#pragma unroll
        for (int ni = 0; ni < 4; ++ni)
#pragma unroll
          for (int rr = 0; rr < 4; ++rr) {
            const int lr = mo * 16 + quad * 4 + rr;
            const int c  = wn * 64 + ni * 16 + r16;
            Ep[lr * 132 + c] = acc[mib + mo][ni][rr];
          }
    }
    __syncthreads();
    if (tid < 191) {
      const int d = tid - 127;
      int k0 = d > 0 ? d : 0;
      int k1 = 128 + d; if (k1 > 64) k1 = 64;
      float s = 0.0f;
      for (int k = k0; k < k1; ++k) s += Ep[k * 132 + (k - d)];
      int dg = dbase + p * 64 + d;
      int sidx = dg % W_DIM;
      if (sidx < 0) sidx += W_DIM;
      atomicAdd(&out[b * W_DIM + sidx], s);
    }
    __syncthreads();
  }
}

// ---------------------------------------------------------------------------
// Fallback (workspace too small): direct fp32.
// ---------------------------------------------------------------------------
__global__ void naive_kernel(const float* __restrict__ x1,
                             const float* __restrict__ x2,
                             float* __restrict__ out) {
  const int s = blockIdx.x;
  const int b = blockIdx.y;
  const int c = threadIdx.x;
  float acc = 0.0f;
  for (int h = 0; h < 4; ++h) {
    const float* p1 = x1 + (size_t)(b * 4 + h) * W_DIM * 256;
    const float* p2 = x2 + (size_t)(b * 4 + h) * W_DIM * 256;
    for (int w = 0; w < W_DIM; ++w) {
      int w1 = s + w + NPAD;
      if (w1 >= W_DIM) w1 -= W_DIM;
      if (w1 >= W_DIM) w1 -= W_DIM;
      acc += p1[(size_t)w1 * 256 + c] * p2[(size_t)w * 256 + c];
    }
  }
  for (int off = 32; off > 0; off >>= 1) acc += __shfl_down(acc, off, 64);
  __shared__ float red[4];
  if ((threadIdx.x & 63) == 0) red[threadIdx.x >> 6] = acc;
  __syncthreads();
  if (threadIdx.x == 0)
    out[b * W_DIM + s] = red[0] + red[1] + red[2] + red[3];
}

extern "C" void kernel_launch(void* const* d_in, const int* in_sizes, int n_in,
                              void* d_out, int out_size, void* d_ws, size_t ws_size,
                              hipStream_t stream) {
  const float* x1 = (const float*)d_in[0];
  const float* x2 = (const float*)d_in[1];
  float* out = (float*)d_out;

  hipMemsetAsync(d_out, 0, (size_t)out_size * sizeof(float), stream);

  const size_t need = (size_t)2 * 16 * BATCH_E * sizeof(unsigned short); // 64 MiB
  if (ws_size >= need) {
    unsigned short* dA = (unsigned short*)d_ws;
    unsigned short* dB = dA + (size_t)16 * BATCH_E;
    convert_kernel<<<dim3(16, 4, 32), 256, 0, stream>>>(x1, x2, dA, dB);
    gemm_band_kernel<<<dim3(512), 256, 0, stream>>>(dA, dB, out);
  } else {
    naive_kernel<<<dim3(W_DIM, 16), 256, 0, stream>>>(x1, x2, out);
  }
}